// Round 16
// baseline (138.969 us; speedup 1.0000x reference)
//
#include <hip/hip_runtime.h>

#define BB   4
#define N1   8192
#define N2   2048
#define KNN  8
#define C1   256
#define C2   512

// main_kernel LDS swizzle: (row&7)<<4 alone leaves rows {0,4,8,12} on the
// same 8 banks for b16 epilogue writes (4-way). Extra (row&8)<<2 bit makes
// the four lk-groups' dword sets disjoint -> 2-way (same-dword halves) only.
#define SWZ(r) ((((r) & 7) << 4) ^ (((r) & 8) << 2))

typedef __attribute__((ext_vector_type(8))) short bf16x8;
typedef __attribute__((ext_vector_type(4))) float f32x4;

// hardware f32->bf16 (RNE) via native __bf16 cast
__device__ __forceinline__ unsigned short f2bf(float x) {
    __bf16 h = (__bf16)x;
    union { __bf16 b; unsigned short u; } v; v.b = h;
    return v.u;
}

// v_med3_u32: median of 3 (no clang builtin; pure-VALU inline asm).
__device__ __forceinline__ unsigned med3u(unsigned a, unsigned b, unsigned c) {
    unsigned d;
    asm("v_med3_u32 %0, %1, %2, %3" : "=v"(d) : "v"(a), "v"(b), "v"(c));
    return d;
}

// Sorted-triple insert in 3 independent ops (depth 1):
//   m1' = min(k,m1); m2' = med3(k,m1,m2); m3' = med3(k,m2,m3)
#define INS3(K, M1, M2, M3)                    \
    {                                          \
        unsigned _k = (K);                     \
        unsigned _n1 = _k < M1 ? _k : M1;      \
        unsigned _n2 = med3u(_k, M1, M2);      \
        unsigned _n3 = med3u(_k, M2, M3);      \
        M1 = _n1; M2 = _n2; M3 = _n3;          \
    }

// Wave64 u32 min-reduction via DPP (VALU pipe) instead of 6x __shfl_xor
// (ds_bpermute). row_shr 1/2/4/8 + row_bcast 15/31 -> lane 63 = global min.
__device__ __forceinline__ unsigned wave_min_bcast_u32(unsigned v) {
    int x = (int)v, d;
    d = __builtin_amdgcn_update_dpp(-1, x, 0x111, 0xF, 0xF, false);  // row_shr:1
    x = ((unsigned)d < (unsigned)x) ? d : x;
    d = __builtin_amdgcn_update_dpp(-1, x, 0x112, 0xF, 0xF, false);  // row_shr:2
    x = ((unsigned)d < (unsigned)x) ? d : x;
    d = __builtin_amdgcn_update_dpp(-1, x, 0x114, 0xF, 0xF, false);  // row_shr:4
    x = ((unsigned)d < (unsigned)x) ? d : x;
    d = __builtin_amdgcn_update_dpp(-1, x, 0x118, 0xF, 0xF, false);  // row_shr:8
    x = ((unsigned)d < (unsigned)x) ? d : x;
    d = __builtin_amdgcn_update_dpp(-1, x, 0x142, 0xF, 0xF, false);  // row_bcast:15
    x = ((unsigned)d < (unsigned)x) ? d : x;
    d = __builtin_amdgcn_update_dpp(-1, x, 0x143, 0xF, 0xF, false);  // row_bcast:31
    x = ((unsigned)d < (unsigned)x) ? d : x;
    return (unsigned)__builtin_amdgcn_readlane(x, 63);               // wave-uniform
}

// r16: KNN scan was LDS-PIPE-bound (96 ds_read_b32/query ~ 557cyc; per-CU
// 71k cyc = 30us floor -- explains r15's med3 null + VALUBusy drop). pos2 now
// staged interleaved [j]=(x,y,z,pad): ONE ds_read_b128 per candidate, wave
// reads contiguous 1KB rows (conflict-free). Same lane mapping, same keys.
#define G0_BLOCKS  (BB * 64)         // 256:  32-pt x 128-ch tiles
#define CW_BLOCKS  256               // 512 threads each -> 131072 elems
#define KNN_BLOCKS (BB * (N1 / 8))   // 4096: 8 queries (8 waves) per block

// ---------------------------------------------------------------------------
// prep_kernel: fused g0 (+BN-fold) + weight-convert + knn.
// ---------------------------------------------------------------------------
__global__ __launch_bounds__(512, 8) void prep_kernel(
    const float* __restrict__ pos1, const float* __restrict__ pos2,
    int* __restrict__ idx_out,
    const float* __restrict__ f2, const float* __restrict__ w10,
    const float* __restrict__ s10, const float* __restrict__ b10,
    float* __restrict__ g0t,
    const float* __restrict__ w11, const float* __restrict__ w12,
    const float* __restrict__ w20,
    unsigned short* __restrict__ w11b, unsigned short* __restrict__ w12b,
    unsigned short* __restrict__ w20b) {

    __shared__ __align__(16) char shmem[32768];
    const int t = threadIdx.x;
    const int bid = blockIdx.x;

    if (bid >= G0_BLOCKS + CW_BLOCKS) {
        // ---- KNN: one wave per query, f32 scan + f64-certified top-8 ----
        const int kbid = bid - G0_BLOCKS - CW_BLOCKS;
        float4* pb4 = (float4*)shmem;          // [N2] (x,y,z,0)
        const int wv = t >> 6, lane = t & 63;
        const int b = kbid >> 10;
        const int n = ((kbid & 1023) << 3) + wv;

        const float* p2b = pos2 + (size_t)b * 3 * N2;
        for (int i = t; i < N2; i += 512)
            pb4[i] = make_float4(p2b[i], p2b[N2 + i], p2b[2 * N2 + i], 0.f);
        __syncthreads();

        const float* p1b = pos1 + (size_t)b * 3 * N1;
        const float qx = p1b[n], qy = p1b[N1 + n], qz = p1b[2 * N1 + n];

        const unsigned INF32 = 0xFFFFFFFFu;
        unsigned m1 = INF32, m2 = INF32, m3 = INF32;

#pragma unroll 4
        for (int i = 0; i < 32; ++i) {
            const int j = i * 64 + lane;
            float4 p = pb4[j];
            float dx = p.x - qx, dy = p.y - qy, dz = p.z - qz;
            float d2 = fmaf(dx, dx, fmaf(dy, dy, dz * dz));
            unsigned k = (__float_as_uint(d2) & 0xFFFFF800u) | (unsigned)j;
            INS3(k, m1, m2, m3)
        }

        int* o = idx_out + ((size_t)b * N1 + n) * KNN;
        unsigned prev = 0;
#pragma unroll 1
        for (int r = 0; r < KNN; ++r) {
            unsigned g = wave_min_bcast_u32(m1);
            if (lane == 0) o[r] = (int)(g & 0x7FFu);
            prev = g;
            bool w = (m1 == g);
            m1 = w ? m2 : m1;
            m2 = w ? m3 : m2;
            m3 = w ? INF32 : m3;
            if (m1 == INF32) {                   // tracked set exhausted (rare)
                unsigned r1 = INF32, r2 = INF32, r3 = INF32;
#pragma unroll 2
                for (int i = 0; i < 32; ++i) {
                    const int j = i * 64 + lane;
                    float4 p = pb4[j];
                    float dx = p.x - qx, dy = p.y - qy, dz = p.z - qz;
                    float d2 = fmaf(dx, dx, fmaf(dy, dy, dz * dz));
                    unsigned k = (__float_as_uint(d2) & 0xFFFFF800u) | (unsigned)j;
                    if (k <= g) k = INF32;       // already extracted
                    INS3(k, r1, r2, r3)
                }
                m1 = r1; m2 = r2; m3 = r3;
            }
        }
        unsigned g9 = wave_min_bcast_u32(m1);
        if ((g9 & 0xFFFFF800u) != (prev & 0xFFFFF800u))
            return;                               // certified (wave-uniform)

        // ---- exact f64 fallback (wave-uniform, ~1 wave per 32k) ----
        const double qxd = (double)qx, qyd = (double)qy, qzd = (double)qz;
        const unsigned long long INF64 = ~0ull;
        unsigned long long M1 = INF64, M2 = INF64;
#pragma unroll 2
        for (int i = 0; i < 32; ++i) {
            const int j = i * 64 + lane;
            float4 p = pb4[j];
            double dx = (double)p.x - qxd;
            double dy = (double)p.y - qyd;
            double dz = (double)p.z - qzd;
            double d2 = dx * dx + dy * dy + dz * dz;
            unsigned long long k =
                (((unsigned long long)__double_as_longlong(d2)) & ~2047ull) | (unsigned)j;
            bool pa = k < M1, pb2 = k < M2;
            M2 = pa ? M1 : (pb2 ? k : M2);
            M1 = pa ? k : M1;
        }
#pragma unroll 1
        for (int r = 0; r < KNN; ++r) {
            unsigned long long g = M1;
#pragma unroll
            for (int s = 32; s; s >>= 1) {
                unsigned long long v = __shfl_xor(g, s, 64);
                g = v < g ? v : g;
            }
            if (lane == 0) o[r] = (int)(g & 2047ull);
            if (M1 == g) {
                if (M2 != INF64) { M1 = M2; M2 = INF64; }
                else {
                    M1 = INF64; M2 = INF64;
#pragma unroll 2
                    for (int i = 0; i < 32; ++i) {
                        const int j = i * 64 + lane;
                        float4 p = pb4[j];
                        double dx = (double)p.x - qxd;
                        double dy = (double)p.y - qyd;
                        double dz = (double)p.z - qzd;
                        double d2 = dx * dx + dy * dy + dz * dz;
                        unsigned long long k =
                            (((unsigned long long)__double_as_longlong(d2)) & ~2047ull) | (unsigned)j;
                        if (k <= g) k = INF64;
                        bool pa = k < M1, pb2 = k < M2;
                        M2 = pa ? M1 : (pb2 ? k : M2);
                        M1 = pa ? k : M1;
                    }
                }
            }
        }
    } else if (bid < G0_BLOCKS) {
        // ---- g0: G0t[b][j][c] = s10[c]*(sum_i f2[b][i][j]*w10[c][i]) + b10[c]
        const int bid2 = bid;
        float (*At)[36]  = (float (*)[36])shmem;            // 4.6 KB
        float (*Wt)[132] = (float (*)[132])(shmem + 4608);  // 16.9 KB
        const int b = bid2 >> 6;
        const int jt = (bid2 & 63) * 32;
        const float* A = f2 + (size_t)b * C2 * N2;

        float acc[4][4];
#pragma unroll
        for (int r = 0; r < 4; ++r)
#pragma unroll
            for (int s = 0; s < 4; ++s) acc[r][s] = 0.f;

        const int lj = t & 31, li4 = (t >> 5) * 4;
        const int wc = t >> 1, wih = (t & 1) * 16;
        const int jg = t & 7, cg = t >> 3;

        for (int i0 = 0; i0 < C2; i0 += 32) {
            __syncthreads();
            if (t < 256) {
#pragma unroll
                for (int u = 0; u < 4; ++u)
                    At[li4 + u][lj] = A[(size_t)(i0 + li4 + u) * N2 + jt + lj];
#pragma unroll
                for (int u = 0; u < 16; ++u)
                    Wt[wih + u][wc] = w10[(size_t)wc * 515 + i0 + wih + u];
            }
            __syncthreads();
            if (t < 256) {
#pragma unroll
                for (int ii = 0; ii < 32; ++ii) {
                    float a[4], w[4];
                    *(float4*)&a[0] = *(const float4*)&At[ii][jg * 4];
                    *(float4*)&w[0] = *(const float4*)&Wt[ii][cg * 4];
#pragma unroll
                    for (int r = 0; r < 4; ++r)
#pragma unroll
                        for (int s = 0; s < 4; ++s) acc[r][s] += a[r] * w[s];
                }
            }
        }
        if (t < 256) {
            float sc0 = s10[cg * 4],     sc1 = s10[cg * 4 + 1];
            float sc2 = s10[cg * 4 + 2], sc3 = s10[cg * 4 + 3];
            float bb0 = b10[cg * 4],     bb1 = b10[cg * 4 + 1];
            float bb2 = b10[cg * 4 + 2], bb3 = b10[cg * 4 + 3];
#pragma unroll
            for (int r = 0; r < 4; ++r) {
                int j = jt + jg * 4 + r;
                *(float4*)&g0t[((size_t)b * N2 + j) * 128 + cg * 4] =
                    make_float4(fmaf(sc0, acc[r][0], bb0), fmaf(sc1, acc[r][1], bb1),
                                fmaf(sc2, acc[r][2], bb2), fmaf(sc3, acc[r][3], bb3));
            }
        }
    } else {
        // ---- weight convert (512 lanes) ----
        int i = (bid - G0_BLOCKS) * 512 + t;
        if (i < 16384)  w11b[i] = f2bf(w11[i]);
        if (i < 32768)  w12b[i] = f2bf(w12[i]);
        if (i < 131072) w20b[i] = f2bf(w20[i]);
    }
}

// ---------------------------------------------------------------------------
// Main fused kernel: 16 queries (128 neighbor-points) per block, 4 waves.
// h0 gather -> L1 (MFMA) -> L2 (MFMA) + max_k -> pooled (bf16, global).
// BN of layer 0 is pre-folded into g0t; wp scaled by s10 at setup.
// ---------------------------------------------------------------------------
__global__ __launch_bounds__(256, 4) void main_kernel(
    const int* __restrict__ idxbuf, const float* __restrict__ g0t,
    const float* __restrict__ pos1, const float* __restrict__ pos2,
    const float* __restrict__ w10, const float* __restrict__ s10,
    const unsigned short* __restrict__ w11b, const float* __restrict__ s11, const float* __restrict__ b11,
    const unsigned short* __restrict__ w12b, const float* __restrict__ s12, const float* __restrict__ b12,
    unsigned short* __restrict__ pooled) {

    __shared__ __align__(16) char smem[37120];
    char* sa = smem;                                         // [128][128] bf16 swz
    float* swp = (float*)(smem + 32768);                     // [3][128] s10*wp
    float* spd = (float*)(smem + 35328);                     // [128][3]
    unsigned short* sidx = (unsigned short*)(smem + 36864);  // [128]

    const int t = threadIdx.x;
    const int lane = t & 63;
    const int wv = t >> 6;
    const int l15 = lane & 15;
    const int lk = lane >> 4;
    const int b = blockIdx.x >> 9;
    const int n0 = (blockIdx.x & 511) << 4;

    if (t < 128) {
        int j = idxbuf[((size_t)b * N1 + n0 + (t >> 3)) * KNN + (t & 7)];
        sidx[t] = (unsigned short)j;
        float s = s10[t];
        swp[t]       = s * w10[(size_t)t * 515 + 512];
        swp[128 + t] = s * w10[(size_t)t * 515 + 513];
        swp[256 + t] = s * w10[(size_t)t * 515 + 514];
        int n = n0 + (t >> 3);
        const float* p2b = pos2 + (size_t)b * 3 * N2;
        const float* p1b = pos1 + (size_t)b * 3 * N1;
        spd[t * 3 + 0] = p2b[j] - p1b[n];
        spd[t * 3 + 1] = p2b[N2 + j] - p1b[N1 + n];
        spd[t * 3 + 2] = p2b[2 * N2 + j] - p1b[2 * N1 + n];
    }
    __syncthreads();

    // ---- Phase A: h0 = relu(g0''[j] + wp'*pd) -> bf16 swz in sa ----
    {
        const int ch0 = (t & 15) * 8;
        const float* g0b = g0t + (size_t)b * N2 * 128;
#pragma unroll
        for (int it = 0; it < 8; ++it) {
            int p = it * 16 + (t >> 4);
            int j = sidx[p];
            const float* gp = g0b + (size_t)j * 128 + ch0;
            float g[8];
            *(float4*)&g[0] = *(const float4*)gp;
            *(float4*)&g[4] = *(const float4*)(gp + 4);
            float pdx = spd[p * 3], pdy = spd[p * 3 + 1], pdz = spd[p * 3 + 2];
            bf16x8 pk;
#pragma unroll
            for (int u = 0; u < 8; ++u) {
                int c = ch0 + u;
                float v = fmaf(swp[c], pdx,
                          fmaf(swp[128 + c], pdy,
                          fmaf(swp[256 + c], pdz, g[u])));
                v = v > 0.f ? v : 0.f;
                pk[u] = (short)f2bf(v);
            }
            int byte = (p * 256 + ch0 * 2) ^ SWZ(p);
            *(bf16x8*)(sa + byte) = pk;
        }
    }
    __syncthreads();

    const f32x4 zf = {0.f, 0.f, 0.f, 0.f};

    // ---- Layer 1: M=128 N=128 K=128 ----
    {
        f32x4 acc[2][8];
#pragma unroll
        for (int m = 0; m < 8; ++m) { acc[0][m] = zf; acc[1][m] = zf; }
        const int nb = wv * 32;
#pragma unroll 2
        for (int k0 = 0; k0 < 4; ++k0) {
            bf16x8 bf0 = *(const bf16x8*)(w11b + (size_t)(nb + l15) * 128 + k0 * 32 + lk * 8);
            bf16x8 bf1 = *(const bf16x8*)(w11b + (size_t)(nb + 16 + l15) * 128 + k0 * 32 + lk * 8);
#pragma unroll
            for (int m = 0; m < 8; ++m) {
                int row = m * 16 + l15;
                int byte = (row * 256 + k0 * 64 + lk * 16) ^ SWZ(row);
                bf16x8 af = *(const bf16x8*)(sa + byte);
                acc[0][m] = __builtin_amdgcn_mfma_f32_16x16x32_bf16(af, bf0, acc[0][m], 0, 0, 0);
                acc[1][m] = __builtin_amdgcn_mfma_f32_16x16x32_bf16(af, bf1, acc[1][m], 0, 0, 0);
            }
        }
        __syncthreads();   // all waves done reading h0
#pragma unroll
        for (int nt = 0; nt < 2; ++nt) {
            int c = nb + nt * 16 + l15;
            float sc = s11[c], bi = b11[c];
#pragma unroll
            for (int m = 0; m < 8; ++m) {
#pragma unroll
                for (int r = 0; r < 4; ++r) {
                    int row = m * 16 + lk * 4 + r;
                    float v = sc * acc[nt][m][r] + bi;
                    v = v > 0.f ? v : 0.f;
                    int byte = (row * 256 + c * 2) ^ SWZ(row);
                    *(unsigned short*)(sa + byte) = f2bf(v);
                }
            }
        }
    }
    __syncthreads();

    // ---- Layer 2: M=128 N=256 K=128; bn/relu, max over k, write pooled ----
    unsigned short* pb = pooled + ((size_t)b * N1 + n0) * 256;
#pragma unroll 1
    for (int h = 0; h < 2; ++h) {
        f32x4 acc2[2][8];
#pragma unroll
        for (int m = 0; m < 8; ++m) { acc2[0][m] = zf; acc2[1][m] = zf; }
        const int nb = h * 128 + wv * 32;
#pragma unroll 2
        for (int k0 = 0; k0 < 4; ++k0) {
            bf16x8 bf0 = *(const bf16x8*)(w12b + (size_t)(nb + l15) * 128 + k0 * 32 + lk * 8);
            bf16x8 bf1 = *(const bf16x8*)(w12b + (size_t)(nb + 16 + l15) * 128 + k0 * 32 + lk * 8);
#pragma unroll
            for (int m = 0; m < 8; ++m) {
                int row = m * 16 + l15;
                int byte = (row * 256 + k0 * 64 + lk * 16) ^ SWZ(row);
                bf16x8 af = *(const bf16x8*)(sa + byte);
                acc2[0][m] = __builtin_amdgcn_mfma_f32_16x16x32_bf16(af, bf0, acc2[0][m], 0, 0, 0);
                acc2[1][m] = __builtin_amdgcn_mfma_f32_16x16x32_bf16(af, bf1, acc2[1][m], 0, 0, 0);
            }
        }
#pragma unroll
        for (int nt = 0; nt < 2; ++nt) {
            int c = nb + nt * 16 + l15;
            float sc = s12[c], bi = b12[c];
#pragma unroll
            for (int m = 0; m < 8; ++m) {
                float mx = 0.f;
#pragma unroll
                for (int r = 0; r < 4; ++r) {
                    float v = sc * acc2[nt][m][r] + bi;
                    v = v > 0.f ? v : 0.f;
                    mx = fmaxf(mx, v);
                }
                mx = fmaxf(mx, __shfl_xor(mx, 16, 64));
                if ((lk & 1) == 0) {
                    int q = m * 2 + (lk >> 1);
                    pb[(size_t)q * 256 + c] = f2bf(mx);
                }
            }
        }
    }
}

// ---------------------------------------------------------------------------
// Final layer: out[b][o][n] = relu(s*(W20 . [pooled|f1]) + b)
// M=32/block, K=512 staged once (feature1 transposed in-kernel), 1 barrier.
// ---------------------------------------------------------------------------
__global__ __launch_bounds__(256, 5) void final_kernel(
    const unsigned short* __restrict__ pooled,
    const float* __restrict__ feature1,
    const unsigned short* __restrict__ w20b,
    const float* __restrict__ s20, const float* __restrict__ b20,
    float* __restrict__ out) {

    __shared__ __align__(16) char sA[32768];   // [32 rows][512 k] bf16, swz
    const int t = threadIdx.x;
    const int lane = t & 63;
    const int wv = t >> 6;
    const int l15 = lane & 15;
    const int lk = lane >> 4;
    const int n0g = blockIdx.x * 32;           // global row base (b*N1+n0)
    const int b = n0g >> 13;
    const int n0 = n0g & (N1 - 1);
    const int obase = wv * 64;

    // ---- stage pooled half: cols 0..255 (fully coalesced 16B/lane) ----
    {
        const unsigned short* pp = pooled + (size_t)n0g * 256;
#pragma unroll
        for (int it = 0; it < 4; ++it) {
            int idx = it * 256 + t;            // 1024 x bf16x8 total
            int row = idx >> 5, c8 = (idx & 31) * 8;
            bf16x8 v = *(const bf16x8*)(pp + idx * 8);
            int byte = (row * 1024 + c8 * 2) ^ ((row & 7) << 4);
            *(bf16x8*)(sA + byte) = v;
        }
    }
    // ---- stage feature1 half: cols 256..511, on-the-fly transpose ----
    {
        const int j = t & 31;                  // query row
        const int cg = (t >> 5) * 32;          // 32-channel chunk
        const float* fp = feature1 + ((size_t)b * C1 + cg) * N1 + n0 + j;
#pragma unroll
        for (int g = 0; g < 4; ++g) {
            unsigned short v[8];
#pragma unroll
            for (int u = 0; u < 8; ++u)
                v[u] = f2bf(fp[(size_t)(g * 8 + u) * N1]);
            int byte = (j * 1024 + (256 + cg + g * 8) * 2) ^ ((j & 7) << 4);
            *(bf16x8*)(sA + byte) = *(bf16x8*)&v[0];
        }
    }
    __syncthreads();

    // ---- GEMM: M=32, N=64/wave, K=512 ----
    f32x4 acc[2][4];
    const f32x4 zf = {0.f, 0.f, 0.f, 0.f};
#pragma unroll
    for (int m = 0; m < 2; ++m)
#pragma unroll
        for (int ot = 0; ot < 4; ++ot) acc[m][ot] = zf;

#pragma unroll 4
    for (int k0 = 0; k0 < 16; ++k0) {
        bf16x8 bfr[4];
#pragma unroll
        for (int ot = 0; ot < 4; ++ot)
            bfr[ot] = *(const bf16x8*)(w20b + (size_t)(obase + ot * 16 + l15) * 512 + k0 * 32 + lk * 8);
#pragma unroll
        for (int m = 0; m < 2; ++m) {
            int row = m * 16 + l15;
            bf16x8 af = *(const bf16x8*)(sA + ((row * 1024 + k0 * 64 + lk * 16) ^ ((row & 7) << 4)));
#pragma unroll
            for (int ot = 0; ot < 4; ++ot)
                acc[m][ot] = __builtin_amdgcn_mfma_f32_16x16x32_bf16(af, bfr[ot], acc[m][ot], 0, 0, 0);
        }
    }

#pragma unroll
    for (int ot = 0; ot < 4; ++ot) {
        int o = obase + ot * 16 + l15;
        float sc = s20[o], bi = b20[o];
#pragma unroll
        for (int m = 0; m < 2; ++m) {
            float4 ov;
            float v0 = sc * acc[m][ot][0] + bi; ov.x = v0 > 0.f ? v0 : 0.f;
            float v1 = sc * acc[m][ot][1] + bi; ov.y = v1 > 0.f ? v1 : 0.f;
            float v2 = sc * acc[m][ot][2] + bi; ov.z = v2 > 0.f ? v2 : 0.f;
            float v3 = sc * acc[m][ot][3] + bi; ov.w = v3 > 0.f ? v3 : 0.f;
            *(float4*)(out + ((size_t)b * 256 + o) * N1 + n0 + m * 16 + lk * 4) = ov;
        }
    }
}

// ---------------------------------------------------------------------------
extern "C" void kernel_launch(void* const* d_in, const int* in_sizes, int n_in,
                              void* d_out, int out_size, void* d_ws, size_t ws_size,
                              hipStream_t stream) {
    (void)in_sizes; (void)n_in; (void)out_size; (void)ws_size;
    const float* pos1     = (const float*)d_in[0];
    const float* pos2     = (const float*)d_in[1];
    const float* feature1 = (const float*)d_in[2];
    const float* feature2 = (const float*)d_in[3];
    const float* w10 = (const float*)d_in[4];
    const float* s10 = (const float*)d_in[5];
    const float* b10 = (const float*)d_in[6];
    const float* w11 = (const float*)d_in[7];
    const float* s11 = (const float*)d_in[8];
    const float* b11 = (const float*)d_in[9];
    const float* w12 = (const float*)d_in[10];
    const float* s12 = (const float*)d_in[11];
    const float* b12 = (const float*)d_in[12];
    const float* w20 = (const float*)d_in[13];
    const float* s20 = (const float*)d_in[14];
    const float* b20 = (const float*)d_in[15];
    float* out = (float*)d_out;

    char* ws = (char*)d_ws;
    int*    idxbuf = (int*)ws;                                   // @0    : 1 MB
    float*  g0t    = (float*)(ws + (1 << 20));                   // @1 MB : 4 MB
    unsigned short* w11b = (unsigned short*)(ws + (5 << 20));    // @5 MB : 32 KB
    unsigned short* w12b = (unsigned short*)(ws + (5 << 20) + 32768);   // 64 KB
    unsigned short* w20b = (unsigned short*)(ws + (5 << 20) + 98304);   // 256 KB
    unsigned short* pooled = (unsigned short*)(ws + (6 << 20));  // @6 MB : 16 MB

    prep_kernel<<<G0_BLOCKS + CW_BLOCKS + KNN_BLOCKS, 512, 0, stream>>>(
        pos1, pos2, idxbuf, feature2, w10, s10, b10, g0t,
        w11, w12, w20, w11b, w12b, w20b);

    main_kernel<<<BB * 512, 256, 0, stream>>>(
        idxbuf, g0t, pos1, pos2,
        w10, s10, w11b, s11, b11, w12b, s12, b12, pooled);

    final_kernel<<<(BB * N1) / 32, 256, 0, stream>>>(pooled, feature1, w20b, s20, b20, out);
}

// Round 17
// 134.198 us; speedup vs baseline: 1.0356x; 1.0356x over previous
//
#include <hip/hip_runtime.h>

#define BB   4
#define N1   8192
#define N2   2048
#define KNN  8
#define C1   256
#define C2   512

// main_kernel LDS swizzle: (row&7)<<4 alone leaves rows {0,4,8,12} on the
// same 8 banks for b16 epilogue writes (4-way). Extra (row&8)<<2 bit makes
// the four lk-groups' dword sets disjoint -> 2-way (same-dword halves) only.
#define SWZ(r) ((((r) & 7) << 4) ^ (((r) & 8) << 2))

typedef __attribute__((ext_vector_type(8))) short bf16x8;
typedef __attribute__((ext_vector_type(4))) float f32x4;

// hardware f32->bf16 (RNE) via native __bf16 cast
__device__ __forceinline__ unsigned short f2bf(float x) {
    __bf16 h = (__bf16)x;
    union { __bf16 b; unsigned short u; } v; v.b = h;
    return v.u;
}

// v_med3_u32: median of 3 (no clang builtin; pure-VALU inline asm).
__device__ __forceinline__ unsigned med3u(unsigned a, unsigned b, unsigned c) {
    unsigned d;
    asm("v_med3_u32 %0, %1, %2, %3" : "=v"(d) : "v"(a), "v"(b), "v"(c));
    return d;
}

// Sorted-triple insert in 3 independent ops (depth 1):
//   m1' = min(k,m1); m2' = med3(k,m1,m2); m3' = med3(k,m2,m3)
#define INS3(K, M1, M2, M3)                    \
    {                                          \
        unsigned _k = (K);                     \
        unsigned _n1 = _k < M1 ? _k : M1;      \
        unsigned _n2 = med3u(_k, M1, M2);      \
        unsigned _n3 = med3u(_k, M2, M3);      \
        M1 = _n1; M2 = _n2; M3 = _n3;          \
    }

// Wave64 u32 min-reduction via DPP (VALU pipe) instead of 6x __shfl_xor
// (ds_bpermute). row_shr 1/2/4/8 + row_bcast 15/31 -> lane 63 = global min.
__device__ __forceinline__ unsigned wave_min_bcast_u32(unsigned v) {
    int x = (int)v, d;
    d = __builtin_amdgcn_update_dpp(-1, x, 0x111, 0xF, 0xF, false);  // row_shr:1
    x = ((unsigned)d < (unsigned)x) ? d : x;
    d = __builtin_amdgcn_update_dpp(-1, x, 0x112, 0xF, 0xF, false);  // row_shr:2
    x = ((unsigned)d < (unsigned)x) ? d : x;
    d = __builtin_amdgcn_update_dpp(-1, x, 0x114, 0xF, 0xF, false);  // row_shr:4
    x = ((unsigned)d < (unsigned)x) ? d : x;
    d = __builtin_amdgcn_update_dpp(-1, x, 0x118, 0xF, 0xF, false);  // row_shr:8
    x = ((unsigned)d < (unsigned)x) ? d : x;
    d = __builtin_amdgcn_update_dpp(-1, x, 0x142, 0xF, 0xF, false);  // row_bcast:15
    x = ((unsigned)d < (unsigned)x) ? d : x;
    d = __builtin_amdgcn_update_dpp(-1, x, 0x143, 0xF, 0xF, false);  // row_bcast:31
    x = ((unsigned)d < (unsigned)x) ? d : x;
    return (unsigned)__builtin_amdgcn_readlane(x, 63);               // wave-uniform
}

// f32 rescan after exhaustion (rare): rebuild top-3 above threshold G.
#define RESCAN3(QX, QY, QZ, G, R1, R2, R3)                                     \
    {                                                                          \
        R1 = INF32; R2 = INF32; R3 = INF32;                                    \
        _Pragma("unroll 2")                                                    \
        for (int i = 0; i < 32; ++i) {                                         \
            const int j = i * 64 + lane;                                       \
            float4 p = pb4[j];                                                 \
            float dx = p.x - (QX), dy = p.y - (QY), dz = p.z - (QZ);           \
            float d2 = fmaf(dx, dx, fmaf(dy, dy, dz * dz));                    \
            unsigned k = (__float_as_uint(d2) & 0xFFFFF800u) | (unsigned)j;    \
            if (k <= (G)) k = INF32;                                           \
            INS3(k, R1, R2, R3)                                                \
        }                                                                      \
    }

// exact f64 fallback (wave-uniform, ~1 query per 32k)
#define F64_FALLBACK(QX, QY, QZ, OPTR)                                         \
    {                                                                          \
        const double qxd = (double)(QX), qyd = (double)(QY), qzd = (double)(QZ);\
        const unsigned long long INF64 = ~0ull;                                \
        unsigned long long M1 = INF64, M2 = INF64;                             \
        _Pragma("unroll 2")                                                    \
        for (int i = 0; i < 32; ++i) {                                         \
            const int j = i * 64 + lane;                                       \
            float4 p = pb4[j];                                                 \
            double dx = (double)p.x - qxd;                                     \
            double dy = (double)p.y - qyd;                                     \
            double dz = (double)p.z - qzd;                                     \
            double d2 = dx * dx + dy * dy + dz * dz;                           \
            unsigned long long k =                                             \
                (((unsigned long long)__double_as_longlong(d2)) & ~2047ull) | (unsigned)j; \
            bool pa = k < M1, pb2 = k < M2;                                    \
            M2 = pa ? M1 : (pb2 ? k : M2);                                     \
            M1 = pa ? k : M1;                                                  \
        }                                                                      \
        _Pragma("unroll 1")                                                    \
        for (int r = 0; r < KNN; ++r) {                                        \
            unsigned long long g = M1;                                         \
            _Pragma("unroll")                                                  \
            for (int s = 32; s; s >>= 1) {                                     \
                unsigned long long v = __shfl_xor(g, s, 64);                   \
                g = v < g ? v : g;                                             \
            }                                                                  \
            if (lane == 0) (OPTR)[r] = (int)(g & 2047ull);                     \
            if (M1 == g) {                                                     \
                if (M2 != INF64) { M1 = M2; M2 = INF64; }                      \
                else {                                                         \
                    M1 = INF64; M2 = INF64;                                    \
                    _Pragma("unroll 1")                                        \
                    for (int i = 0; i < 32; ++i) {                             \
                        const int j = i * 64 + lane;                           \
                        float4 p = pb4[j];                                     \
                        double dx = (double)p.x - qxd;                         \
                        double dy = (double)p.y - qyd;                         \
                        double dz = (double)p.z - qzd;                         \
                        double d2 = dx * dx + dy * dy + dz * dz;               \
                        unsigned long long k =                                 \
                            (((unsigned long long)__double_as_longlong(d2)) & ~2047ull) | (unsigned)j; \
                        if (k <= g) k = INF64;                                 \
                        bool pa = k < M1, pb2 = k < M2;                        \
                        M2 = pa ? M1 : (pb2 ? k : M2);                        \
                        M1 = pa ? k : M1;                                      \
                    }                                                          \
                }                                                              \
            }                                                                  \
        }                                                                      \
    }

// r17: TWO queries per wave -- each pb4[j] row load serves both queries
// (LDS ops/query halved), the two DPP extraction chains interleave (serial
// latency hidden), two INS3 chains give the scan ILP. Per-query algorithm,
// keys, certification, fallback identical. 16 queries/block -> 2048 blocks.
#define G0_BLOCKS  (BB * 64)          // 256:  32-pt x 128-ch tiles
#define CW_BLOCKS  256                // 512 threads each -> 131072 elems
#define KNN_BLOCKS (BB * (N1 / 16))   // 2048: 16 queries (8 waves x 2) / block

// ---------------------------------------------------------------------------
// prep_kernel: fused g0 (+BN-fold) + weight-convert + knn.
// ---------------------------------------------------------------------------
__global__ __launch_bounds__(512, 8) void prep_kernel(
    const float* __restrict__ pos1, const float* __restrict__ pos2,
    int* __restrict__ idx_out,
    const float* __restrict__ f2, const float* __restrict__ w10,
    const float* __restrict__ s10, const float* __restrict__ b10,
    float* __restrict__ g0t,
    const float* __restrict__ w11, const float* __restrict__ w12,
    const float* __restrict__ w20,
    unsigned short* __restrict__ w11b, unsigned short* __restrict__ w12b,
    unsigned short* __restrict__ w20b) {

    __shared__ __align__(16) char shmem[32768];
    const int t = threadIdx.x;
    const int bid = blockIdx.x;

    if (bid >= G0_BLOCKS + CW_BLOCKS) {
        // ---- KNN: one wave per TWO queries, f32 scan + f64-certified top-8
        const int kbid = bid - G0_BLOCKS - CW_BLOCKS;
        float4* pb4 = (float4*)shmem;          // [N2] (x,y,z,0)
        const int wv = t >> 6, lane = t & 63;
        const int b = kbid >> 9;
        const int nA = ((kbid & 511) << 4) + wv * 2;
        const int nB = nA + 1;

        const float* p2b = pos2 + (size_t)b * 3 * N2;
        for (int i = t; i < N2; i += 512)
            pb4[i] = make_float4(p2b[i], p2b[N2 + i], p2b[2 * N2 + i], 0.f);
        __syncthreads();

        const float* p1b = pos1 + (size_t)b * 3 * N1;
        const float qxA = p1b[nA], qyA = p1b[N1 + nA], qzA = p1b[2 * N1 + nA];
        const float qxB = p1b[nB], qyB = p1b[N1 + nB], qzB = p1b[2 * N1 + nB];

        const unsigned INF32 = 0xFFFFFFFFu;
        unsigned A1 = INF32, A2 = INF32, A3 = INF32;
        unsigned B1 = INF32, B2 = INF32, B3 = INF32;

#pragma unroll 2
        for (int i = 0; i < 32; ++i) {
            const int j = i * 64 + lane;
            float4 p = pb4[j];
            float dxA = p.x - qxA, dyA = p.y - qyA, dzA = p.z - qzA;
            float d2A = fmaf(dxA, dxA, fmaf(dyA, dyA, dzA * dzA));
            unsigned kA = (__float_as_uint(d2A) & 0xFFFFF800u) | (unsigned)j;
            float dxB = p.x - qxB, dyB = p.y - qyB, dzB = p.z - qzB;
            float d2B = fmaf(dxB, dxB, fmaf(dyB, dyB, dzB * dzB));
            unsigned kB = (__float_as_uint(d2B) & 0xFFFFF800u) | (unsigned)j;
            INS3(kA, A1, A2, A3)
            INS3(kB, B1, B2, B3)
        }

        int* oA = idx_out + ((size_t)b * N1 + nA) * KNN;
        int* oB = idx_out + ((size_t)b * N1 + nB) * KNN;
        unsigned prevA = 0, prevB = 0;
#pragma unroll 1
        for (int r = 0; r < KNN; ++r) {
            unsigned gA = wave_min_bcast_u32(A1);
            unsigned gB = wave_min_bcast_u32(B1);
            if (lane == 0) { oA[r] = (int)(gA & 0x7FFu); oB[r] = (int)(gB & 0x7FFu); }
            prevA = gA; prevB = gB;
            bool wA = (A1 == gA);
            A1 = wA ? A2 : A1;
            A2 = wA ? A3 : A2;
            A3 = wA ? INF32 : A3;
            bool wB = (B1 == gB);
            B1 = wB ? B2 : B1;
            B2 = wB ? B3 : B2;
            B3 = wB ? INF32 : B3;
            if (A1 == INF32) {                   // exhausted (rare)
                unsigned r1, r2, r3;
                RESCAN3(qxA, qyA, qzA, gA, r1, r2, r3)
                A1 = r1; A2 = r2; A3 = r3;
            }
            if (B1 == INF32) {
                unsigned r1, r2, r3;
                RESCAN3(qxB, qyB, qzB, gB, r1, r2, r3)
                B1 = r1; B2 = r2; B3 = r3;
            }
        }
        unsigned g9A = wave_min_bcast_u32(A1);
        unsigned g9B = wave_min_bcast_u32(B1);
        if ((g9A & 0xFFFFF800u) == (prevA & 0xFFFFF800u)) {   // uncertified A
            F64_FALLBACK(qxA, qyA, qzA, oA)
        }
        if ((g9B & 0xFFFFF800u) == (prevB & 0xFFFFF800u)) {   // uncertified B
            F64_FALLBACK(qxB, qyB, qzB, oB)
        }
    } else if (bid < G0_BLOCKS) {
        // ---- g0: G0t[b][j][c] = s10[c]*(sum_i f2[b][i][j]*w10[c][i]) + b10[c]
        const int bid2 = bid;
        float (*At)[36]  = (float (*)[36])shmem;            // 4.6 KB
        float (*Wt)[132] = (float (*)[132])(shmem + 4608);  // 16.9 KB
        const int b = bid2 >> 6;
        const int jt = (bid2 & 63) * 32;
        const float* A = f2 + (size_t)b * C2 * N2;

        float acc[4][4];
#pragma unroll
        for (int r = 0; r < 4; ++r)
#pragma unroll
            for (int s = 0; s < 4; ++s) acc[r][s] = 0.f;

        const int lj = t & 31, li4 = (t >> 5) * 4;
        const int wc = t >> 1, wih = (t & 1) * 16;
        const int jg = t & 7, cg = t >> 3;

        for (int i0 = 0; i0 < C2; i0 += 32) {
            __syncthreads();
            if (t < 256) {
#pragma unroll
                for (int u = 0; u < 4; ++u)
                    At[li4 + u][lj] = A[(size_t)(i0 + li4 + u) * N2 + jt + lj];
#pragma unroll
                for (int u = 0; u < 16; ++u)
                    Wt[wih + u][wc] = w10[(size_t)wc * 515 + i0 + wih + u];
            }
            __syncthreads();
            if (t < 256) {
#pragma unroll
                for (int ii = 0; ii < 32; ++ii) {
                    float a[4], w[4];
                    *(float4*)&a[0] = *(const float4*)&At[ii][jg * 4];
                    *(float4*)&w[0] = *(const float4*)&Wt[ii][cg * 4];
#pragma unroll
                    for (int r = 0; r < 4; ++r)
#pragma unroll
                        for (int s = 0; s < 4; ++s) acc[r][s] += a[r] * w[s];
                }
            }
        }
        if (t < 256) {
            float sc0 = s10[cg * 4],     sc1 = s10[cg * 4 + 1];
            float sc2 = s10[cg * 4 + 2], sc3 = s10[cg * 4 + 3];
            float bb0 = b10[cg * 4],     bb1 = b10[cg * 4 + 1];
            float bb2 = b10[cg * 4 + 2], bb3 = b10[cg * 4 + 3];
#pragma unroll
            for (int r = 0; r < 4; ++r) {
                int j = jt + jg * 4 + r;
                *(float4*)&g0t[((size_t)b * N2 + j) * 128 + cg * 4] =
                    make_float4(fmaf(sc0, acc[r][0], bb0), fmaf(sc1, acc[r][1], bb1),
                                fmaf(sc2, acc[r][2], bb2), fmaf(sc3, acc[r][3], bb3));
            }
        }
    } else {
        // ---- weight convert (512 lanes) ----
        int i = (bid - G0_BLOCKS) * 512 + t;
        if (i < 16384)  w11b[i] = f2bf(w11[i]);
        if (i < 32768)  w12b[i] = f2bf(w12[i]);
        if (i < 131072) w20b[i] = f2bf(w20[i]);
    }
}

// ---------------------------------------------------------------------------
// Main fused kernel: 16 queries (128 neighbor-points) per block, 4 waves.
// h0 gather -> L1 (MFMA) -> L2 (MFMA) + max_k -> pooled (bf16, global).
// BN of layer 0 is pre-folded into g0t; wp scaled by s10 at setup.
// ---------------------------------------------------------------------------
__global__ __launch_bounds__(256, 4) void main_kernel(
    const int* __restrict__ idxbuf, const float* __restrict__ g0t,
    const float* __restrict__ pos1, const float* __restrict__ pos2,
    const float* __restrict__ w10, const float* __restrict__ s10,
    const unsigned short* __restrict__ w11b, const float* __restrict__ s11, const float* __restrict__ b11,
    const unsigned short* __restrict__ w12b, const float* __restrict__ s12, const float* __restrict__ b12,
    unsigned short* __restrict__ pooled) {

    __shared__ __align__(16) char smem[37120];
    char* sa = smem;                                         // [128][128] bf16 swz
    float* swp = (float*)(smem + 32768);                     // [3][128] s10*wp
    float* spd = (float*)(smem + 35328);                     // [128][3]
    unsigned short* sidx = (unsigned short*)(smem + 36864);  // [128]

    const int t = threadIdx.x;
    const int lane = t & 63;
    const int wv = t >> 6;
    const int l15 = lane & 15;
    const int lk = lane >> 4;
    const int b = blockIdx.x >> 9;
    const int n0 = (blockIdx.x & 511) << 4;

    if (t < 128) {
        int j = idxbuf[((size_t)b * N1 + n0 + (t >> 3)) * KNN + (t & 7)];
        sidx[t] = (unsigned short)j;
        float s = s10[t];
        swp[t]       = s * w10[(size_t)t * 515 + 512];
        swp[128 + t] = s * w10[(size_t)t * 515 + 513];
        swp[256 + t] = s * w10[(size_t)t * 515 + 514];
        int n = n0 + (t >> 3);
        const float* p2b = pos2 + (size_t)b * 3 * N2;
        const float* p1b = pos1 + (size_t)b * 3 * N1;
        spd[t * 3 + 0] = p2b[j] - p1b[n];
        spd[t * 3 + 1] = p2b[N2 + j] - p1b[N1 + n];
        spd[t * 3 + 2] = p2b[2 * N2 + j] - p1b[2 * N1 + n];
    }
    __syncthreads();

    // ---- Phase A: h0 = relu(g0''[j] + wp'*pd) -> bf16 swz in sa ----
    {
        const int ch0 = (t & 15) * 8;
        const float* g0b = g0t + (size_t)b * N2 * 128;
#pragma unroll
        for (int it = 0; it < 8; ++it) {
            int p = it * 16 + (t >> 4);
            int j = sidx[p];
            const float* gp = g0b + (size_t)j * 128 + ch0;
            float g[8];
            *(float4*)&g[0] = *(const float4*)gp;
            *(float4*)&g[4] = *(const float4*)(gp + 4);
            float pdx = spd[p * 3], pdy = spd[p * 3 + 1], pdz = spd[p * 3 + 2];
            bf16x8 pk;
#pragma unroll
            for (int u = 0; u < 8; ++u) {
                int c = ch0 + u;
                float v = fmaf(swp[c], pdx,
                          fmaf(swp[128 + c], pdy,
                          fmaf(swp[256 + c], pdz, g[u])));
                v = v > 0.f ? v : 0.f;
                pk[u] = (short)f2bf(v);
            }
            int byte = (p * 256 + ch0 * 2) ^ SWZ(p);
            *(bf16x8*)(sa + byte) = pk;
        }
    }
    __syncthreads();

    const f32x4 zf = {0.f, 0.f, 0.f, 0.f};

    // ---- Layer 1: M=128 N=128 K=128 ----
    {
        f32x4 acc[2][8];
#pragma unroll
        for (int m = 0; m < 8; ++m) { acc[0][m] = zf; acc[1][m] = zf; }
        const int nb = wv * 32;
#pragma unroll 2
        for (int k0 = 0; k0 < 4; ++k0) {
            bf16x8 bf0 = *(const bf16x8*)(w11b + (size_t)(nb + l15) * 128 + k0 * 32 + lk * 8);
            bf16x8 bf1 = *(const bf16x8*)(w11b + (size_t)(nb + 16 + l15) * 128 + k0 * 32 + lk * 8);
#pragma unroll
            for (int m = 0; m < 8; ++m) {
                int row = m * 16 + l15;
                int byte = (row * 256 + k0 * 64 + lk * 16) ^ SWZ(row);
                bf16x8 af = *(const bf16x8*)(sa + byte);
                acc[0][m] = __builtin_amdgcn_mfma_f32_16x16x32_bf16(af, bf0, acc[0][m], 0, 0, 0);
                acc[1][m] = __builtin_amdgcn_mfma_f32_16x16x32_bf16(af, bf1, acc[1][m], 0, 0, 0);
            }
        }
        __syncthreads();   // all waves done reading h0
#pragma unroll
        for (int nt = 0; nt < 2; ++nt) {
            int c = nb + nt * 16 + l15;
            float sc = s11[c], bi = b11[c];
#pragma unroll
            for (int m = 0; m < 8; ++m) {
#pragma unroll
                for (int r = 0; r < 4; ++r) {
                    int row = m * 16 + lk * 4 + r;
                    float v = sc * acc[nt][m][r] + bi;
                    v = v > 0.f ? v : 0.f;
                    int byte = (row * 256 + c * 2) ^ SWZ(row);
                    *(unsigned short*)(sa + byte) = f2bf(v);
                }
            }
        }
    }
    __syncthreads();

    // ---- Layer 2: M=128 N=256 K=128; bn/relu, max over k, write pooled ----
    unsigned short* pb = pooled + ((size_t)b * N1 + n0) * 256;
#pragma unroll 1
    for (int h = 0; h < 2; ++h) {
        f32x4 acc2[2][8];
#pragma unroll
        for (int m = 0; m < 8; ++m) { acc2[0][m] = zf; acc2[1][m] = zf; }
        const int nb = h * 128 + wv * 32;
#pragma unroll 2
        for (int k0 = 0; k0 < 4; ++k0) {
            bf16x8 bf0 = *(const bf16x8*)(w12b + (size_t)(nb + l15) * 128 + k0 * 32 + lk * 8);
            bf16x8 bf1 = *(const bf16x8*)(w12b + (size_t)(nb + 16 + l15) * 128 + k0 * 32 + lk * 8);
#pragma unroll
            for (int m = 0; m < 8; ++m) {
                int row = m * 16 + l15;
                int byte = (row * 256 + k0 * 64 + lk * 16) ^ SWZ(row);
                bf16x8 af = *(const bf16x8*)(sa + byte);
                acc2[0][m] = __builtin_amdgcn_mfma_f32_16x16x32_bf16(af, bf0, acc2[0][m], 0, 0, 0);
                acc2[1][m] = __builtin_amdgcn_mfma_f32_16x16x32_bf16(af, bf1, acc2[1][m], 0, 0, 0);
            }
        }
#pragma unroll
        for (int nt = 0; nt < 2; ++nt) {
            int c = nb + nt * 16 + l15;
            float sc = s12[c], bi = b12[c];
#pragma unroll
            for (int m = 0; m < 8; ++m) {
                float mx = 0.f;
#pragma unroll
                for (int r = 0; r < 4; ++r) {
                    float v = sc * acc2[nt][m][r] + bi;
                    v = v > 0.f ? v : 0.f;
                    mx = fmaxf(mx, v);
                }
                mx = fmaxf(mx, __shfl_xor(mx, 16, 64));
                if ((lk & 1) == 0) {
                    int q = m * 2 + (lk >> 1);
                    pb[(size_t)q * 256 + c] = f2bf(mx);
                }
            }
        }
    }
}

// ---------------------------------------------------------------------------
// Final layer: out[b][o][n] = relu(s*(W20 . [pooled|f1]) + b)
// M=32/block, K=512 staged once (feature1 transposed in-kernel), 1 barrier.
// ---------------------------------------------------------------------------
__global__ __launch_bounds__(256, 5) void final_kernel(
    const unsigned short* __restrict__ pooled,
    const float* __restrict__ feature1,
    const unsigned short* __restrict__ w20b,
    const float* __restrict__ s20, const float* __restrict__ b20,
    float* __restrict__ out) {

    __shared__ __align__(16) char sA[32768];   // [32 rows][512 k] bf16, swz
    const int t = threadIdx.x;
    const int lane = t & 63;
    const int wv = t >> 6;
    const int l15 = lane & 15;
    const int lk = lane >> 4;
    const int n0g = blockIdx.x * 32;           // global row base (b*N1+n0)
    const int b = n0g >> 13;
    const int n0 = n0g & (N1 - 1);
    const int obase = wv * 64;

    // ---- stage pooled half: cols 0..255 (fully coalesced 16B/lane) ----
    {
        const unsigned short* pp = pooled + (size_t)n0g * 256;
#pragma unroll
        for (int it = 0; it < 4; ++it) {
            int idx = it * 256 + t;            // 1024 x bf16x8 total
            int row = idx >> 5, c8 = (idx & 31) * 8;
            bf16x8 v = *(const bf16x8*)(pp + idx * 8);
            int byte = (row * 1024 + c8 * 2) ^ ((row & 7) << 4);
            *(bf16x8*)(sA + byte) = v;
        }
    }
    // ---- stage feature1 half: cols 256..511, on-the-fly transpose ----
    {
        const int j = t & 31;                  // query row
        const int cg = (t >> 5) * 32;          // 32-channel chunk
        const float* fp = feature1 + ((size_t)b * C1 + cg) * N1 + n0 + j;
#pragma unroll
        for (int g = 0; g < 4; ++g) {
            unsigned short v[8];
#pragma unroll
            for (int u = 0; u < 8; ++u)
                v[u] = f2bf(fp[(size_t)(g * 8 + u) * N1]);
            int byte = (j * 1024 + (256 + cg + g * 8) * 2) ^ ((j & 7) << 4);
            *(bf16x8*)(sA + byte) = *(bf16x8*)&v[0];
        }
    }
    __syncthreads();

    // ---- GEMM: M=32, N=64/wave, K=512 ----
    f32x4 acc[2][4];
    const f32x4 zf = {0.f, 0.f, 0.f, 0.f};
#pragma unroll
    for (int m = 0; m < 2; ++m)
#pragma unroll
        for (int ot = 0; ot < 4; ++ot) acc[m][ot] = zf;

#pragma unroll 4
    for (int k0 = 0; k0 < 16; ++k0) {
        bf16x8 bfr[4];
#pragma unroll
        for (int ot = 0; ot < 4; ++ot)
            bfr[ot] = *(const bf16x8*)(w20b + (size_t)(obase + ot * 16 + l15) * 512 + k0 * 32 + lk * 8);
#pragma unroll
        for (int m = 0; m < 2; ++m) {
            int row = m * 16 + l15;
            bf16x8 af = *(const bf16x8*)(sA + ((row * 1024 + k0 * 64 + lk * 16) ^ ((row & 7) << 4)));
#pragma unroll
            for (int ot = 0; ot < 4; ++ot)
                acc[m][ot] = __builtin_amdgcn_mfma_f32_16x16x32_bf16(af, bfr[ot], acc[m][ot], 0, 0, 0);
        }
    }

#pragma unroll
    for (int ot = 0; ot < 4; ++ot) {
        int o = obase + ot * 16 + l15;
        float sc = s20[o], bi = b20[o];
#pragma unroll
        for (int m = 0; m < 2; ++m) {
            float4 ov;
            float v0 = sc * acc[m][ot][0] + bi; ov.x = v0 > 0.f ? v0 : 0.f;
            float v1 = sc * acc[m][ot][1] + bi; ov.y = v1 > 0.f ? v1 : 0.f;
            float v2 = sc * acc[m][ot][2] + bi; ov.z = v2 > 0.f ? v2 : 0.f;
            float v3 = sc * acc[m][ot][3] + bi; ov.w = v3 > 0.f ? v3 : 0.f;
            *(float4*)(out + ((size_t)b * 256 + o) * N1 + n0 + m * 16 + lk * 4) = ov;
        }
    }
}

// ---------------------------------------------------------------------------
extern "C" void kernel_launch(void* const* d_in, const int* in_sizes, int n_in,
                              void* d_out, int out_size, void* d_ws, size_t ws_size,
                              hipStream_t stream) {
    (void)in_sizes; (void)n_in; (void)out_size; (void)ws_size;
    const float* pos1     = (const float*)d_in[0];
    const float* pos2     = (const float*)d_in[1];
    const float* feature1 = (const float*)d_in[2];
    const float* feature2 = (const float*)d_in[3];
    const float* w10 = (const float*)d_in[4];
    const float* s10 = (const float*)d_in[5];
    const float* b10 = (const float*)d_in[6];
    const float* w11 = (const float*)d_in[7];
    const float* s11 = (const float*)d_in[8];
    const float* b11 = (const float*)d_in[9];
    const float* w12 = (const float*)d_in[10];
    const float* s12 = (const float*)d_in[11];
    const float* b12 = (const float*)d_in[12];
    const float* w20 = (const float*)d_in[13];
    const float* s20 = (const float*)d_in[14];
    const float* b20 = (const float*)d_in[15];
    float* out = (float*)d_out;

    char* ws = (char*)d_ws;
    int*    idxbuf = (int*)ws;                                   // @0    : 1 MB
    float*  g0t    = (float*)(ws + (1 << 20));                   // @1 MB : 4 MB
    unsigned short* w11b = (unsigned short*)(ws + (5 << 20));    // @5 MB : 32 KB
    unsigned short* w12b = (unsigned short*)(ws + (5 << 20) + 32768);   // 64 KB
    unsigned short* w20b = (unsigned short*)(ws + (5 << 20) + 98304);   // 256 KB
    unsigned short* pooled = (unsigned short*)(ws + (6 << 20));  // @6 MB : 16 MB

    prep_kernel<<<G0_BLOCKS + CW_BLOCKS + KNN_BLOCKS, 512, 0, stream>>>(
        pos1, pos2, idxbuf, feature2, w10, s10, b10, g0t,
        w11, w12, w20, w11b, w12b, w20b);

    main_kernel<<<BB * 512, 256, 0, stream>>>(
        idxbuf, g0t, pos1, pos2,
        w10, s10, w11b, s11, b11, w12b, s12, b12, pooled);

    final_kernel<<<(BB * N1) / 32, 256, 0, stream>>>(pooled, feature1, w20b, s20, b20, out);
}